// Round 16
// baseline (238.812 us; speedup 1.0000x reference)
//
#include <hip/hip_runtime.h>
#include <hip/hip_bf16.h>

using short8 = __attribute__((ext_vector_type(8))) short;
using s16x4  = __attribute__((ext_vector_type(4))) short;
using f32x4  = __attribute__((ext_vector_type(4))) float;
using int4v  = __attribute__((ext_vector_type(4))) int;

#define HW 4096
#define CC 128
#define DH 32
#define NH 4

__device__ inline float bf2f(unsigned short u) {
    unsigned int x = ((unsigned int)u) << 16;
    return __builtin_bit_cast(float, x);
}
__device__ inline unsigned short f2bf(float f) {
    unsigned int x = __builtin_bit_cast(unsigned int, f);
    unsigned int lsb = (x >> 16) & 1u;
    x += 0x7fffu + lsb;
    return (unsigned short)(x >> 16);
}
__device__ inline float ldf(const void* p, size_t i, bool f32) {
    return f32 ? ((const float*)p)[i] : bf2f(((const unsigned short*)p)[i]);
}
__device__ inline float fexp2(float x) { return __builtin_amdgcn_exp2f(x); }
// truncation-pack 8 positive floats -> bf16x8 (li stays f32-exact)
__device__ inline short8 pack8(const float* e) {
    int4v p;
#pragma unroll
    for (int t = 0; t < 4; t++) {
        unsigned lo = __builtin_bit_cast(unsigned, e[2 * t])     >> 16;
        unsigned hi = __builtin_bit_cast(unsigned, e[2 * t + 1]) & 0xffff0000u;
        p[t] = (int)(lo | hi);
    }
    return __builtin_bit_cast(short8, p);
}
// inline wave-uniform dtype detect: 1 load + ballot on xA[0..63] (L2-hot)
__device__ inline bool detect_f32(const void* xA) {
    unsigned int w = ((const unsigned int*)xA)[threadIdx.x & 63];
    float a = fabsf(bf2f((unsigned short)(w & 0xffffu)));
    bool bad = !(a >= 1e-6f && a <= 1e4f);
    return __popcll(__ballot(bad)) > 32;   // f32 mantissa junk ~89% implausible
}

// ---------------- prep: gn channel sums (blocks 0..255) + cvt (256..319) -----
// raw2[2][128][2]: per-channel {sum, sumsq}, written non-atomically.
__global__ void prep_kernel(const void* __restrict__ xA, const void* __restrict__ xB,
                            const void* __restrict__ qA, const void* __restrict__ qB,
                            const void* __restrict__ oA, const void* __restrict__ oB,
                            const void* __restrict__ bA, const void* __restrict__ bB,
                            float* __restrict__ raw2,
                            unsigned short* __restrict__ Wc) {
    const bool f32 = detect_f32(xA);
    const int b = blockIdx.x;
    if (b < 256) {
        const int s = b >> 7, c = b & 127;
        const void* x = s ? xB : xA;
        float sum = 0.f, sumsq = 0.f;
        for (int p = threadIdx.x; p < HW; p += 256) {
            float v = ldf(x, (size_t)c * HW + p, f32);
            sum += v; sumsq += v * v;
        }
        for (int off = 32; off; off >>= 1) {
            sum   += __shfl_down(sum, off);
            sumsq += __shfl_down(sumsq, off);
        }
        __shared__ float smem[8];
        int w = threadIdx.x >> 6;
        if ((threadIdx.x & 63) == 0) { smem[w] = sum; smem[4 + w] = sumsq; }
        __syncthreads();
        if (threadIdx.x == 0) {
            raw2[(s * 128 + c) * 2]     = smem[0] + smem[1] + smem[2] + smem[3];
            raw2[(s * 128 + c) * 2 + 1] = smem[4] + smem[5] + smem[6] + smem[7];
        }
    } else {
        for (int i = (b - 256) * 256 + threadIdx.x; i < 131328; i += 64 * 256) {
            const void* s; int off;
            if      (i < 49152)  { s = qA; off = i; }
            else if (i < 98304)  { s = qB; off = i - 49152; }
            else if (i < 114688) { s = oA; off = i - 98304; }
            else if (i < 131072) { s = oB; off = i - 114688; }
            else if (i < 131200) { s = bA; off = i - 131072; }
            else                 { s = bB; off = i - 131200; }
            Wc[i] = f2bf(ldf(s, off, f32));
        }
    }
}

// ---------------- gn_apply: stats inline + normalize + transpose -> xn -------
__global__ void gn_apply(const void* __restrict__ xA, const void* __restrict__ xB,
                         const void* __restrict__ gw, const void* __restrict__ gb,
                         const float* __restrict__ raw2,
                         unsigned short* __restrict__ xn) {
    const bool f32 = detect_f32(xA);
    const int s = blockIdx.y;
    const int p0 = blockIdx.x * 32;
    const void* x = s ? xB : xA;
    const int tid = threadIdx.x;
    __shared__ float st[16][2];
    __shared__ float tile[128][33];   // [c][p], 16.9 KB
    if (tid < 16) {
        float s1 = 0.f, s2 = 0.f;
#pragma unroll
        for (int c = 0; c < 8; c++) {
            s1 += raw2[(s * 128 + tid * 8 + c) * 2];
            s2 += raw2[(s * 128 + tid * 8 + c) * 2 + 1];
        }
        const float NEL = 8.0f * HW;
        float mu = s1 / NEL;
        float var = s2 / NEL - mu * mu;
        st[tid][0] = mu;
        st[tid][1] = rsqrtf(var + 1e-5f);
    }
    __syncthreads();
    const int pl = tid & 31;
#pragma unroll
    for (int cc = 0; cc < 16; cc++) {
        int c = cc * 8 + (tid >> 5);
        float v = ldf(x, (size_t)c * HW + p0 + pl, f32);
        tile[c][pl] = (v - st[c >> 3][0]) * st[c >> 3][1] * ldf(gw, c, f32)
                    + ldf(gb, c, f32);
    }
    __syncthreads();
    // coalesced transposed writes as u32 pairs: 32p x 64 u32
    unsigned int* xo = (unsigned int*)(xn + (size_t)s * HW * CC);
#pragma unroll
    for (int k = 0; k < 8; k++) {
        int idx = tid + k * 256;
        int p = idx >> 6, c2 = idx & 63;
        unsigned lo = (unsigned)f2bf(tile[2 * c2][p]);
        unsigned hi = (unsigned)f2bf(tile[2 * c2 + 1][p]);
        xo[((size_t)(p0 + p) * CC >> 1) + c2] = lo | (hi << 16);
    }
}

// ---------------- KV GEMM: K as [z*NH+h][seq][32]; V pre-swizzled ------------
__global__ void qkv_kernel(const unsigned short* __restrict__ Wc,
                           const unsigned short* __restrict__ xn,
                           unsigned short* __restrict__ Kt,
                           unsigned short* __restrict__ Vp) {
    const int z = blockIdx.z;
    const unsigned short* Wq = Wc + (size_t)z * 49152;
    const int o0 = blockIdx.x * 16;
    const int w = threadIdx.x >> 6, lane = threadIdx.x & 63;
    const int quad = lane >> 4, col = lane & 15;
    const int p0 = blockIdx.y * 64 + w * 16;
    const unsigned short* xb = xn + (size_t)z * HW * CC;
    f32x4 acc = {0.f, 0.f, 0.f, 0.f};
#pragma unroll
    for (int kc = 0; kc < 4; kc++) {
        short8 a = *(const short8*)(Wq + (size_t)(o0 + col) * CC + kc * 32 + quad * 8);
        short8 b = *(const short8*)(xb + (size_t)(p0 + col) * CC + kc * 32 + quad * 8);
        acc = __builtin_amdgcn_mfma_f32_16x16x32_bf16(a, b, acc, 0, 0, 0);
    }
#pragma unroll
    for (int r = 0; r < 4; r++) {
        int o = o0 + quad * 4 + r;
        int h = o / 96, rr = o % 96;
        int p = p0 + col;
        unsigned short vb = f2bf(acc[r]);
        if (rr >= 32 && rr < 64) {
            Kt[((size_t)(z * NH + h) * HW + p) * DH + (rr - 32)] = vb;
        } else if (rr >= 64) {
            int d = rr - 64;
            int jb = p >> 6, jl = p & 63;
            int sub = jl >> 5, jm = jl & 31;
            int qp, jj;
            if (jm < 16) { qp = jm >> 2; jj = jm & 3; }
            else         { qp = (jm - 16) >> 2; jj = 4 + ((jm - 16) & 3); }
            int frag  = (d >> 4) + sub * 2;
            int lanep = qp * 16 + (d & 15);
            Vp[(((size_t)(z * NH + h) * 64 + jb) * 2048)
               + frag * 512 + lanep * 8 + jj] = vb;
        }
    }
}

// ---------------- Flash attention: i-tile 32, 8 waves = 8 j-chunks of 512 ----
__global__ __launch_bounds__(512, 8) void attn_kernel(
        const unsigned short* __restrict__ Wc,
        const unsigned short* __restrict__ xn,
        const unsigned short* __restrict__ Kt_all,
        const unsigned short* __restrict__ Vp_all,
        unsigned short* __restrict__ OT_all) {
    const int z = blockIdx.z, h = blockIdx.y;
    const int tid = threadIdx.x;
    const int wave = tid >> 6, lane = tid & 63;
    const int quad = lane >> 4, col = lane & 15;
    const int sc = wave;            // j-chunk 0..7 (512 j each)
    const int zq = 1 - z;
    const unsigned short* Kt = Kt_all + (size_t)(z * NH + h) * HW * DH;
    const unsigned short* Vp = Vp_all + (size_t)(z * NH + h) * 64 * 2048;
    unsigned short* OT = OT_all + (size_t)z * HW * CC;

    const int i0 = blockIdx.x * 32;

    __shared__ __align__(16) short qlds[32][40];           // 2.5 KB (pad 40)
    __shared__ float ldsO[8][2][32][17];                   // 34.8 KB
    __shared__ float ldsl[8][32];                          // 1 KB

    // ---- recompute Q: waves 0..3 -> (subtile w>>1, d-half w&1), pre-scaled ---
    if (wave < 4) {
        const float kscale = 0.12751569782174257f;  // (1/sqrt(128))*log2(e)
        const int stq = wave >> 1, dcq = wave & 1;
        const unsigned short* Wq = Wc + (size_t)zq * 49152 + (size_t)(96 * h) * CC;
        const unsigned short* xq = xn + (size_t)zq * HW * CC;
        f32x4 qa = {0.f, 0.f, 0.f, 0.f};
#pragma unroll
        for (int kc = 0; kc < 4; kc++) {
            short8 a = *(const short8*)(Wq + (size_t)(dcq * 16 + col) * CC + kc * 32 + quad * 8);
            short8 b = *(const short8*)(xq + (size_t)(i0 + stq * 16 + col) * CC + kc * 32 + quad * 8);
            qa = __builtin_amdgcn_mfma_f32_16x16x32_bf16(a, b, qa, 0, 0, 0);
        }
#pragma unroll
        for (int r = 0; r < 4; r++)
            qlds[stq * 16 + col][dcq * 16 + quad * 4 + r] = (short)f2bf(qa[r] * kscale);
    }
    __syncthreads();

    f32x4 acc0[2], acc1[2];
    float li[2];
#pragma unroll
    for (int s = 0; s < 2; s++) {
        acc0[s] = (f32x4){0.f, 0.f, 0.f, 0.f};
        acc1[s] = (f32x4){0.f, 0.f, 0.f, 0.f};
        li[s] = 0.f;
    }

    const int jb = sc * 512;
    for (int j0 = jb; j0 < jb + 512; j0 += 64) {
        short8 kf[4];
#pragma unroll
        for (int X = 0; X < 4; X++)
            kf[X] = *(const short8*)(Kt + (size_t)(j0 + X * 16 + col) * DH + quad * 8);
        const unsigned short* vb_ = Vp + (size_t)(j0 >> 6) * 2048 + lane * 8;
        short8 va0 = *(const short8*)(vb_);
        short8 va1 = *(const short8*)(vb_ + 512);
        short8 va2 = *(const short8*)(vb_ + 1024);
        short8 va3 = *(const short8*)(vb_ + 1536);
#pragma unroll
        for (int s = 0; s < 2; s++) {
            short8 qf = *(const short8*)(&qlds[s * 16 + col][quad * 8]);
            f32x4 zero = {0.f, 0.f, 0.f, 0.f};
            f32x4 st0 = __builtin_amdgcn_mfma_f32_16x16x32_bf16(kf[0], qf, zero, 0, 0, 0);
            f32x4 st1 = __builtin_amdgcn_mfma_f32_16x16x32_bf16(kf[1], qf, zero, 0, 0, 0);
            f32x4 st2 = __builtin_amdgcn_mfma_f32_16x16x32_bf16(kf[2], qf, zero, 0, 0, 0);
            f32x4 st3 = __builtin_amdgcn_mfma_f32_16x16x32_bf16(kf[3], qf, zero, 0, 0, 0);
            float e[16], l0 = 0.f, l1 = 0.f;
#pragma unroll
            for (int r = 0; r < 4; r++) {
                e[r]      = fexp2(st0[r]);
                e[4 + r]  = fexp2(st1[r]);
                e[8 + r]  = fexp2(st2[r]);
                e[12 + r] = fexp2(st3[r]);
                l0 += e[r] + e[4 + r];
                l1 += e[8 + r] + e[12 + r];
            }
            li[s] += l0 + l1;
            short8 pb0 = pack8(&e[0]);
            short8 pb1 = pack8(&e[8]);
            acc0[s] = __builtin_amdgcn_mfma_f32_16x16x32_bf16(va0, pb0, acc0[s], 0, 0, 0);
            acc1[s] = __builtin_amdgcn_mfma_f32_16x16x32_bf16(va1, pb0, acc1[s], 0, 0, 0);
            acc0[s] = __builtin_amdgcn_mfma_f32_16x16x32_bf16(va2, pb1, acc0[s], 0, 0, 0);
            acc1[s] = __builtin_amdgcn_mfma_f32_16x16x32_bf16(va3, pb1, acc1[s], 0, 0, 0);
        }
    }
#pragma unroll
    for (int s = 0; s < 2; s++) {
        li[s] += __shfl_xor(li[s], 16);
        li[s] += __shfl_xor(li[s], 32);
#pragma unroll
        for (int r = 0; r < 4; r++) {
            ldsO[sc][s][quad * 4 + r][col]      = acc0[s][r];
            ldsO[sc][s][16 + quad * 4 + r][col] = acc1[s][r];
        }
        if (quad == 0) ldsl[sc][s * 16 + col] = li[s];
    }
    __syncthreads();
    // ---- combine 8 chunks (plain sums; bounded logits) ----
#pragma unroll
    for (int k = 0; k < 2; k++) {
        int idx = tid + k * 512;
        int il = idx >> 5, d = idx & 31;
        int itc = il >> 4, cc2 = il & 15;
        float L = 0.f, O = 0.f;
#pragma unroll
        for (int c8 = 0; c8 < 8; c8++) {
            L += ldsl[c8][il];
            O += ldsO[c8][itc][d][cc2];
        }
        OT[(size_t)(i0 + il) * CC + h * DH + d] = f2bf(O / L);
    }
}

// ---------------- Out proj + bias + f32 residual (stats inline) --------------
__global__ void proj_kernel(const unsigned short* __restrict__ Wc,
                            const unsigned short* __restrict__ OT_all,
                            const void* __restrict__ xA,
                            const void* __restrict__ xB,
                            const void* __restrict__ gw,
                            const void* __restrict__ gb,
                            const float* __restrict__ raw2,
                            float* __restrict__ out) {
    const bool f32 = detect_f32(xA);
    const int z = blockIdx.z;
    const unsigned short* Wp = Wc + 98304 + (size_t)z * 16384;
    const unsigned short* bp = Wc + 131072 + (size_t)z * 128;
    const void* xz = z ? xB : xA;
    const int tid = threadIdx.x;
    __shared__ float st[16][2];
    if (tid < 16) {
        float s1 = 0.f, s2 = 0.f;
#pragma unroll
        for (int c = 0; c < 8; c++) {
            s1 += raw2[(z * 128 + tid * 8 + c) * 2];
            s2 += raw2[(z * 128 + tid * 8 + c) * 2 + 1];
        }
        const float NEL = 8.0f * HW;
        float mu = s1 / NEL;
        float var = s2 / NEL - mu * mu;
        st[tid][0] = mu;
        st[tid][1] = rsqrtf(var + 1e-5f);
    }
    __syncthreads();
    const int o0 = blockIdx.x * 16;
    const int w = tid >> 6, lane = tid & 63;
    const int quad = lane >> 4, col = lane & 15;
    const int p0 = blockIdx.y * 64 + w * 16;
    const unsigned short* ob = OT_all + (size_t)z * HW * CC;
    f32x4 acc = {0.f, 0.f, 0.f, 0.f};
#pragma unroll
    for (int kc = 0; kc < 4; kc++) {
        short8 a = *(const short8*)(Wp + (size_t)(o0 + col) * CC + kc * 32 + quad * 8);
        short8 b = *(const short8*)(ob + (size_t)(p0 + col) * CC + kc * 32 + quad * 8);
        acc = __builtin_amdgcn_mfma_f32_16x16x32_bf16(a, b, acc, 0, 0, 0);
    }
    const int p = p0 + col;
#pragma unroll
    for (int r = 0; r < 4; r++) {
        int o = o0 + quad * 4 + r;
        float xv = ldf(xz, (size_t)o * HW + p, f32);
        float res = (xv - st[o >> 3][0]) * st[o >> 3][1] * ldf(gw, o, f32)
                  + ldf(gb, o, f32);
        out[(size_t)z * CC * HW + (size_t)o * HW + p] = acc[r] + bf2f(bp[o]) + res;
    }
}

extern "C" void kernel_launch(void* const* d_in, const int* in_sizes, int n_in,
                              void* d_out, int out_size, void* d_ws, size_t ws_size,
                              hipStream_t stream) {
    (void)in_sizes; (void)n_in; (void)out_size; (void)ws_size;
    const void* xA    = d_in[0];
    const void* xB    = d_in[1];
    const void* gnw   = d_in[2];
    const void* gnb   = d_in[3];
    const void* qkvAw = d_in[4];
    const void* outAw = d_in[5];
    const void* outAb = d_in[6];
    const void* qkvBw = d_in[7];
    const void* outBw = d_in[8];
    const void* outBb = d_in[9];

    // workspace: 9 MB total
    char* ws = (char*)d_ws;
    float*          raw2 = (float*)(ws);                        // 2 KB [2][128][2]
    unsigned short* Wc   = (unsigned short*)(ws + 4096);        // 257 KB
    unsigned short* Kt   = (unsigned short*)(ws + (1u << 20));  // 2 MB [2][4][4096][32]
    unsigned short* Vp   = (unsigned short*)(ws + (3u << 20));  // 2 MB swizzled V
    unsigned short* OT   = (unsigned short*)(ws + (5u << 20));  // 2 MB [2][4096][128]
    unsigned short* xn   = (unsigned short*)(ws + (7u << 20));  // 2 MB [2][4096][128]

    prep_kernel<<<320, 256, 0, stream>>>(xA, xB, qkvAw, qkvBw, outAw, outBw,
                                         outAb, outBb, raw2, Wc);
    gn_apply<<<dim3(128, 2), 256, 0, stream>>>(xA, xB, gnw, gnb, raw2, xn);
    qkv_kernel<<<dim3(24, 64, 2), 256, 0, stream>>>(Wc, xn, Kt, Vp);
    attn_kernel<<<dim3(128, NH, 2), 512, 0, stream>>>(Wc, xn, Kt, Vp, OT);
    proj_kernel<<<dim3(8, 64, 2), 256, 0, stream>>>(Wc, OT, xA, xB, gnw, gnb,
                                                    raw2, (float*)d_out);
}

// Round 17
// 141.054 us; speedup vs baseline: 1.6931x; 1.6931x over previous
//
#include <hip/hip_runtime.h>
#include <hip/hip_bf16.h>

using short8 = __attribute__((ext_vector_type(8))) short;
using s16x4  = __attribute__((ext_vector_type(4))) short;
using f32x4  = __attribute__((ext_vector_type(4))) float;
using int4v  = __attribute__((ext_vector_type(4))) int;

#define HW 4096
#define CC 128
#define DH 32
#define NH 4

__device__ inline float bf2f(unsigned short u) {
    unsigned int x = ((unsigned int)u) << 16;
    return __builtin_bit_cast(float, x);
}
__device__ inline unsigned short f2bf(float f) {
    unsigned int x = __builtin_bit_cast(unsigned int, f);
    unsigned int lsb = (x >> 16) & 1u;
    x += 0x7fffu + lsb;
    return (unsigned short)(x >> 16);
}
__device__ inline float ldf(const void* p, size_t i, bool f32) {
    return f32 ? ((const float*)p)[i] : bf2f(((const unsigned short*)p)[i]);
}
__device__ inline float fexp2(float x) { return __builtin_amdgcn_exp2f(x); }
// truncation-pack 8 positive floats -> bf16x8 (li stays f32-exact)
__device__ inline short8 pack8(const float* e) {
    int4v p;
#pragma unroll
    for (int t = 0; t < 4; t++) {
        unsigned lo = __builtin_bit_cast(unsigned, e[2 * t])     >> 16;
        unsigned hi = __builtin_bit_cast(unsigned, e[2 * t + 1]) & 0xffff0000u;
        p[t] = (int)(lo | hi);
    }
    return __builtin_bit_cast(short8, p);
}
// inline wave-uniform dtype detect: 1 load + ballot on xA[0..63] (L2-hot)
__device__ inline bool detect_f32(const void* xA) {
    unsigned int w = ((const unsigned int*)xA)[threadIdx.x & 63];
    float a = fabsf(bf2f((unsigned short)(w & 0xffffu)));
    bool bad = !(a >= 1e-6f && a <= 1e4f);
    return __popcll(__ballot(bad)) > 32;   // f32 mantissa junk ~89% implausible
}

// ---------------- prep: gn channel sums (blocks 0..255) + cvt (256..319) -----
// raw2[2][128][2]: per-channel {sum, sumsq}, written non-atomically.
__global__ void prep_kernel(const void* __restrict__ xA, const void* __restrict__ xB,
                            const void* __restrict__ qA, const void* __restrict__ qB,
                            const void* __restrict__ oA, const void* __restrict__ oB,
                            const void* __restrict__ bA, const void* __restrict__ bB,
                            float* __restrict__ raw2,
                            unsigned short* __restrict__ Wc) {
    const bool f32 = detect_f32(xA);
    const int b = blockIdx.x;
    if (b < 256) {
        const int s = b >> 7, c = b & 127;
        const void* x = s ? xB : xA;
        float sum = 0.f, sumsq = 0.f;
        for (int p = threadIdx.x; p < HW; p += 256) {
            float v = ldf(x, (size_t)c * HW + p, f32);
            sum += v; sumsq += v * v;
        }
        for (int off = 32; off; off >>= 1) {
            sum   += __shfl_down(sum, off);
            sumsq += __shfl_down(sumsq, off);
        }
        __shared__ float smem[8];
        int w = threadIdx.x >> 6;
        if ((threadIdx.x & 63) == 0) { smem[w] = sum; smem[4 + w] = sumsq; }
        __syncthreads();
        if (threadIdx.x == 0) {
            raw2[(s * 128 + c) * 2]     = smem[0] + smem[1] + smem[2] + smem[3];
            raw2[(s * 128 + c) * 2 + 1] = smem[4] + smem[5] + smem[6] + smem[7];
        }
    } else {
        for (int i = (b - 256) * 256 + threadIdx.x; i < 131328; i += 64 * 256) {
            const void* s; int off;
            if      (i < 49152)  { s = qA; off = i; }
            else if (i < 98304)  { s = qB; off = i - 49152; }
            else if (i < 114688) { s = oA; off = i - 98304; }
            else if (i < 131072) { s = oB; off = i - 114688; }
            else if (i < 131200) { s = bA; off = i - 131072; }
            else                 { s = bB; off = i - 131200; }
            Wc[i] = f2bf(ldf(s, off, f32));
        }
    }
}

// ---------------- gn_apply: stats inline + normalize + transpose -> xn -------
__global__ void gn_apply(const void* __restrict__ xA, const void* __restrict__ xB,
                         const void* __restrict__ gw, const void* __restrict__ gb,
                         const float* __restrict__ raw2,
                         unsigned short* __restrict__ xn) {
    const bool f32 = detect_f32(xA);
    const int s = blockIdx.y;
    const int p0 = blockIdx.x * 32;
    const void* x = s ? xB : xA;
    const int tid = threadIdx.x;
    __shared__ float st[16][2];
    __shared__ float tile[128][33];   // [c][p], 16.9 KB
    if (tid < 16) {
        float s1 = 0.f, s2 = 0.f;
#pragma unroll
        for (int c = 0; c < 8; c++) {
            s1 += raw2[(s * 128 + tid * 8 + c) * 2];
            s2 += raw2[(s * 128 + tid * 8 + c) * 2 + 1];
        }
        const float NEL = 8.0f * HW;
        float mu = s1 / NEL;
        float var = s2 / NEL - mu * mu;
        st[tid][0] = mu;
        st[tid][1] = rsqrtf(var + 1e-5f);
    }
    __syncthreads();
    const int pl = tid & 31;
#pragma unroll
    for (int cc = 0; cc < 16; cc++) {
        int c = cc * 8 + (tid >> 5);
        float v = ldf(x, (size_t)c * HW + p0 + pl, f32);
        tile[c][pl] = (v - st[c >> 3][0]) * st[c >> 3][1] * ldf(gw, c, f32)
                    + ldf(gb, c, f32);
    }
    __syncthreads();
    // coalesced transposed writes as u32 pairs: 32p x 64 u32
    unsigned int* xo = (unsigned int*)(xn + (size_t)s * HW * CC);
#pragma unroll
    for (int k = 0; k < 8; k++) {
        int idx = tid + k * 256;
        int p = idx >> 6, c2 = idx & 63;
        unsigned lo = (unsigned)f2bf(tile[2 * c2][p]);
        unsigned hi = (unsigned)f2bf(tile[2 * c2 + 1][p]);
        xo[((size_t)(p0 + p) * CC >> 1) + c2] = lo | (hi << 16);
    }
}

// ---------------- KV GEMM: K as [z*NH+h][seq][32]; V pre-swizzled ------------
__global__ void qkv_kernel(const unsigned short* __restrict__ Wc,
                           const unsigned short* __restrict__ xn,
                           unsigned short* __restrict__ Kt,
                           unsigned short* __restrict__ Vp) {
    const int z = blockIdx.z;
    const unsigned short* Wq = Wc + (size_t)z * 49152;
    const int o0 = blockIdx.x * 16;
    const int w = threadIdx.x >> 6, lane = threadIdx.x & 63;
    const int quad = lane >> 4, col = lane & 15;
    const int p0 = blockIdx.y * 64 + w * 16;
    const unsigned short* xb = xn + (size_t)z * HW * CC;
    f32x4 acc = {0.f, 0.f, 0.f, 0.f};
#pragma unroll
    for (int kc = 0; kc < 4; kc++) {
        short8 a = *(const short8*)(Wq + (size_t)(o0 + col) * CC + kc * 32 + quad * 8);
        short8 b = *(const short8*)(xb + (size_t)(p0 + col) * CC + kc * 32 + quad * 8);
        acc = __builtin_amdgcn_mfma_f32_16x16x32_bf16(a, b, acc, 0, 0, 0);
    }
#pragma unroll
    for (int r = 0; r < 4; r++) {
        int o = o0 + quad * 4 + r;
        int h = o / 96, rr = o % 96;
        int p = p0 + col;
        unsigned short vb = f2bf(acc[r]);
        if (rr >= 32 && rr < 64) {
            Kt[((size_t)(z * NH + h) * HW + p) * DH + (rr - 32)] = vb;
        } else if (rr >= 64) {
            int d = rr - 64;
            int jb = p >> 6, jl = p & 63;
            int sub = jl >> 5, jm = jl & 31;
            int qp, jj;
            if (jm < 16) { qp = jm >> 2; jj = jm & 3; }
            else         { qp = (jm - 16) >> 2; jj = 4 + ((jm - 16) & 3); }
            int frag  = (d >> 4) + sub * 2;
            int lanep = qp * 16 + (d & 15);
            Vp[(((size_t)(z * NH + h) * 64 + jb) * 2048)
               + frag * 512 + lanep * 8 + jj] = vb;
        }
    }
}

// ---------------- Flash attention: i-tile 32, 8 waves = 8 j-chunks of 512 ----
// __launch_bounds__(512, 4): 128-VGPR cap. Round 16's (512,8) forced a 64-VGPR
// cap -> scratch spill (WRITE_SIZE 12.8->327 MB, 3x slowdown). With the cap
// relaxed the allocator fits ~64 VGPRs and HW can still run 8 waves/SIMD.
__global__ __launch_bounds__(512, 4) void attn_kernel(
        const unsigned short* __restrict__ Wc,
        const unsigned short* __restrict__ xn,
        const unsigned short* __restrict__ Kt_all,
        const unsigned short* __restrict__ Vp_all,
        unsigned short* __restrict__ OT_all) {
    const int z = blockIdx.z, h = blockIdx.y;
    const int tid = threadIdx.x;
    const int wave = tid >> 6, lane = tid & 63;
    const int quad = lane >> 4, col = lane & 15;
    const int sc = wave;            // j-chunk 0..7 (512 j each)
    const int zq = 1 - z;
    const unsigned short* Kt = Kt_all + (size_t)(z * NH + h) * HW * DH;
    const unsigned short* Vp = Vp_all + (size_t)(z * NH + h) * 64 * 2048;
    unsigned short* OT = OT_all + (size_t)z * HW * CC;

    const int i0 = blockIdx.x * 32;

    __shared__ __align__(16) short qlds[32][40];           // 2.5 KB (pad 40)
    __shared__ float ldsO[8][2][32][17];                   // 34.8 KB
    __shared__ float ldsl[8][32];                          // 1 KB

    // ---- recompute Q: waves 0..3 -> (subtile w>>1, d-half w&1), pre-scaled ---
    if (wave < 4) {
        const float kscale = 0.12751569782174257f;  // (1/sqrt(128))*log2(e)
        const int stq = wave >> 1, dcq = wave & 1;
        const unsigned short* Wq = Wc + (size_t)zq * 49152 + (size_t)(96 * h) * CC;
        const unsigned short* xq = xn + (size_t)zq * HW * CC;
        f32x4 qa = {0.f, 0.f, 0.f, 0.f};
#pragma unroll
        for (int kc = 0; kc < 4; kc++) {
            short8 a = *(const short8*)(Wq + (size_t)(dcq * 16 + col) * CC + kc * 32 + quad * 8);
            short8 b = *(const short8*)(xq + (size_t)(i0 + stq * 16 + col) * CC + kc * 32 + quad * 8);
            qa = __builtin_amdgcn_mfma_f32_16x16x32_bf16(a, b, qa, 0, 0, 0);
        }
#pragma unroll
        for (int r = 0; r < 4; r++)
            qlds[stq * 16 + col][dcq * 16 + quad * 4 + r] = (short)f2bf(qa[r] * kscale);
    }
    __syncthreads();

    f32x4 acc0[2], acc1[2];
    float li[2];
#pragma unroll
    for (int s = 0; s < 2; s++) {
        acc0[s] = (f32x4){0.f, 0.f, 0.f, 0.f};
        acc1[s] = (f32x4){0.f, 0.f, 0.f, 0.f};
        li[s] = 0.f;
    }

    const int jb = sc * 512;
    for (int j0 = jb; j0 < jb + 512; j0 += 64) {
        short8 kf[4];
#pragma unroll
        for (int X = 0; X < 4; X++)
            kf[X] = *(const short8*)(Kt + (size_t)(j0 + X * 16 + col) * DH + quad * 8);
        const unsigned short* vb_ = Vp + (size_t)(j0 >> 6) * 2048 + lane * 8;
        short8 va0 = *(const short8*)(vb_);
        short8 va1 = *(const short8*)(vb_ + 512);
        short8 va2 = *(const short8*)(vb_ + 1024);
        short8 va3 = *(const short8*)(vb_ + 1536);
#pragma unroll
        for (int s = 0; s < 2; s++) {
            short8 qf = *(const short8*)(&qlds[s * 16 + col][quad * 8]);
            f32x4 zero = {0.f, 0.f, 0.f, 0.f};
            f32x4 st0 = __builtin_amdgcn_mfma_f32_16x16x32_bf16(kf[0], qf, zero, 0, 0, 0);
            f32x4 st1 = __builtin_amdgcn_mfma_f32_16x16x32_bf16(kf[1], qf, zero, 0, 0, 0);
            f32x4 st2 = __builtin_amdgcn_mfma_f32_16x16x32_bf16(kf[2], qf, zero, 0, 0, 0);
            f32x4 st3 = __builtin_amdgcn_mfma_f32_16x16x32_bf16(kf[3], qf, zero, 0, 0, 0);
            float e[16], l0 = 0.f, l1 = 0.f;
#pragma unroll
            for (int r = 0; r < 4; r++) {
                e[r]      = fexp2(st0[r]);
                e[4 + r]  = fexp2(st1[r]);
                e[8 + r]  = fexp2(st2[r]);
                e[12 + r] = fexp2(st3[r]);
                l0 += e[r] + e[4 + r];
                l1 += e[8 + r] + e[12 + r];
            }
            li[s] += l0 + l1;
            short8 pb0 = pack8(&e[0]);
            short8 pb1 = pack8(&e[8]);
            acc0[s] = __builtin_amdgcn_mfma_f32_16x16x32_bf16(va0, pb0, acc0[s], 0, 0, 0);
            acc1[s] = __builtin_amdgcn_mfma_f32_16x16x32_bf16(va1, pb0, acc1[s], 0, 0, 0);
            acc0[s] = __builtin_amdgcn_mfma_f32_16x16x32_bf16(va2, pb1, acc0[s], 0, 0, 0);
            acc1[s] = __builtin_amdgcn_mfma_f32_16x16x32_bf16(va3, pb1, acc1[s], 0, 0, 0);
        }
    }
#pragma unroll
    for (int s = 0; s < 2; s++) {
        li[s] += __shfl_xor(li[s], 16);
        li[s] += __shfl_xor(li[s], 32);
#pragma unroll
        for (int r = 0; r < 4; r++) {
            ldsO[sc][s][quad * 4 + r][col]      = acc0[s][r];
            ldsO[sc][s][16 + quad * 4 + r][col] = acc1[s][r];
        }
        if (quad == 0) ldsl[sc][s * 16 + col] = li[s];
    }
    __syncthreads();
    // ---- combine 8 chunks (plain sums; bounded logits) ----
#pragma unroll
    for (int k = 0; k < 2; k++) {
        int idx = tid + k * 512;
        int il = idx >> 5, d = idx & 31;
        int itc = il >> 4, cc2 = il & 15;
        float L = 0.f, O = 0.f;
#pragma unroll
        for (int c8 = 0; c8 < 8; c8++) {
            L += ldsl[c8][il];
            O += ldsO[c8][itc][d][cc2];
        }
        OT[(size_t)(i0 + il) * CC + h * DH + d] = f2bf(O / L);
    }
}

// ---------------- Out proj + bias + f32 residual (stats inline) --------------
__global__ void proj_kernel(const unsigned short* __restrict__ Wc,
                            const unsigned short* __restrict__ OT_all,
                            const void* __restrict__ xA,
                            const void* __restrict__ xB,
                            const void* __restrict__ gw,
                            const void* __restrict__ gb,
                            const float* __restrict__ raw2,
                            float* __restrict__ out) {
    const bool f32 = detect_f32(xA);
    const int z = blockIdx.z;
    const unsigned short* Wp = Wc + 98304 + (size_t)z * 16384;
    const unsigned short* bp = Wc + 131072 + (size_t)z * 128;
    const void* xz = z ? xB : xA;
    const int tid = threadIdx.x;
    __shared__ float st[16][2];
    if (tid < 16) {
        float s1 = 0.f, s2 = 0.f;
#pragma unroll
        for (int c = 0; c < 8; c++) {
            s1 += raw2[(z * 128 + tid * 8 + c) * 2];
            s2 += raw2[(z * 128 + tid * 8 + c) * 2 + 1];
        }
        const float NEL = 8.0f * HW;
        float mu = s1 / NEL;
        float var = s2 / NEL - mu * mu;
        st[tid][0] = mu;
        st[tid][1] = rsqrtf(var + 1e-5f);
    }
    __syncthreads();
    const int o0 = blockIdx.x * 16;
    const int w = tid >> 6, lane = tid & 63;
    const int quad = lane >> 4, col = lane & 15;
    const int p0 = blockIdx.y * 64 + w * 16;
    const unsigned short* ob = OT_all + (size_t)z * HW * CC;
    f32x4 acc = {0.f, 0.f, 0.f, 0.f};
#pragma unroll
    for (int kc = 0; kc < 4; kc++) {
        short8 a = *(const short8*)(Wp + (size_t)(o0 + col) * CC + kc * 32 + quad * 8);
        short8 b = *(const short8*)(ob + (size_t)(p0 + col) * CC + kc * 32 + quad * 8);
        acc = __builtin_amdgcn_mfma_f32_16x16x32_bf16(a, b, acc, 0, 0, 0);
    }
    const int p = p0 + col;
#pragma unroll
    for (int r = 0; r < 4; r++) {
        int o = o0 + quad * 4 + r;
        float xv = ldf(xz, (size_t)o * HW + p, f32);
        float res = (xv - st[o >> 3][0]) * st[o >> 3][1] * ldf(gw, o, f32)
                  + ldf(gb, o, f32);
        out[(size_t)z * CC * HW + (size_t)o * HW + p] = acc[r] + bf2f(bp[o]) + res;
    }
}

extern "C" void kernel_launch(void* const* d_in, const int* in_sizes, int n_in,
                              void* d_out, int out_size, void* d_ws, size_t ws_size,
                              hipStream_t stream) {
    (void)in_sizes; (void)n_in; (void)out_size; (void)ws_size;
    const void* xA    = d_in[0];
    const void* xB    = d_in[1];
    const void* gnw   = d_in[2];
    const void* gnb   = d_in[3];
    const void* qkvAw = d_in[4];
    const void* outAw = d_in[5];
    const void* outAb = d_in[6];
    const void* qkvBw = d_in[7];
    const void* outBw = d_in[8];
    const void* outBb = d_in[9];

    // workspace: 9 MB total
    char* ws = (char*)d_ws;
    float*          raw2 = (float*)(ws);                        // 2 KB [2][128][2]
    unsigned short* Wc   = (unsigned short*)(ws + 4096);        // 257 KB
    unsigned short* Kt   = (unsigned short*)(ws + (1u << 20));  // 2 MB [2][4][4096][32]
    unsigned short* Vp   = (unsigned short*)(ws + (3u << 20));  // 2 MB swizzled V
    unsigned short* OT   = (unsigned short*)(ws + (5u << 20));  // 2 MB [2][4096][128]
    unsigned short* xn   = (unsigned short*)(ws + (7u << 20));  // 2 MB [2][4096][128]

    prep_kernel<<<320, 256, 0, stream>>>(xA, xB, qkvAw, qkvBw, outAw, outBw,
                                         outAb, outBb, raw2, Wc);
    gn_apply<<<dim3(128, 2), 256, 0, stream>>>(xA, xB, gnw, gnb, raw2, xn);
    qkv_kernel<<<dim3(24, 64, 2), 256, 0, stream>>>(Wc, xn, Kt, Vp);
    attn_kernel<<<dim3(128, NH, 2), 512, 0, stream>>>(Wc, xn, Kt, Vp, OT);
    proj_kernel<<<dim3(8, 64, 2), 256, 0, stream>>>(Wc, OT, xA, xB, gnw, gnb,
                                                    raw2, (float*)d_out);
}

// Round 18
// 129.077 us; speedup vs baseline: 1.8502x; 1.0928x over previous
//
#include <hip/hip_runtime.h>
#include <hip/hip_bf16.h>

using short8 = __attribute__((ext_vector_type(8))) short;
using s16x4  = __attribute__((ext_vector_type(4))) short;
using f32x4  = __attribute__((ext_vector_type(4))) float;
using int4v  = __attribute__((ext_vector_type(4))) int;

#define HW 4096
#define CC 128
#define DH 32
#define NH 4

__device__ inline float bf2f(unsigned short u) {
    unsigned int x = ((unsigned int)u) << 16;
    return __builtin_bit_cast(float, x);
}
__device__ inline unsigned short f2bf(float f) {
    unsigned int x = __builtin_bit_cast(unsigned int, f);
    unsigned int lsb = (x >> 16) & 1u;
    x += 0x7fffu + lsb;
    return (unsigned short)(x >> 16);
}
__device__ inline float ldf(const void* p, size_t i, bool f32) {
    return f32 ? ((const float*)p)[i] : bf2f(((const unsigned short*)p)[i]);
}
__device__ inline float fexp2(float x) { return __builtin_amdgcn_exp2f(x); }
// truncation-pack 8 positive floats -> bf16x8 (li stays f32-exact)
__device__ inline short8 pack8(const float* e) {
    int4v p;
#pragma unroll
    for (int t = 0; t < 4; t++) {
        unsigned lo = __builtin_bit_cast(unsigned, e[2 * t])     >> 16;
        unsigned hi = __builtin_bit_cast(unsigned, e[2 * t + 1]) & 0xffff0000u;
        p[t] = (int)(lo | hi);
    }
    return __builtin_bit_cast(short8, p);
}
// inline wave-uniform dtype detect: 1 load + ballot on xA[0..63] (L2-hot)
__device__ inline bool detect_f32(const void* xA) {
    unsigned int w = ((const unsigned int*)xA)[threadIdx.x & 63];
    float a = fabsf(bf2f((unsigned short)(w & 0xffffu)));
    bool bad = !(a >= 1e-6f && a <= 1e4f);
    return __popcll(__ballot(bad)) > 32;   // f32 mantissa junk ~89% implausible
}

// ---------------- prep: gn channel sums (blocks 0..255) + cvt (256..319) -----
// raw2[2][128][2]: per-channel {sum, sumsq}, written non-atomically.
__global__ void prep_kernel(const void* __restrict__ xA, const void* __restrict__ xB,
                            const void* __restrict__ qA, const void* __restrict__ qB,
                            const void* __restrict__ oA, const void* __restrict__ oB,
                            const void* __restrict__ bA, const void* __restrict__ bB,
                            float* __restrict__ raw2,
                            unsigned short* __restrict__ Wc) {
    const bool f32 = detect_f32(xA);
    const int b = blockIdx.x;
    if (b < 256) {
        const int s = b >> 7, c = b & 127;
        const void* x = s ? xB : xA;
        float sum = 0.f, sumsq = 0.f;
        for (int p = threadIdx.x; p < HW; p += 256) {
            float v = ldf(x, (size_t)c * HW + p, f32);
            sum += v; sumsq += v * v;
        }
        for (int off = 32; off; off >>= 1) {
            sum   += __shfl_down(sum, off);
            sumsq += __shfl_down(sumsq, off);
        }
        __shared__ float smem[8];
        int w = threadIdx.x >> 6;
        if ((threadIdx.x & 63) == 0) { smem[w] = sum; smem[4 + w] = sumsq; }
        __syncthreads();
        if (threadIdx.x == 0) {
            raw2[(s * 128 + c) * 2]     = smem[0] + smem[1] + smem[2] + smem[3];
            raw2[(s * 128 + c) * 2 + 1] = smem[4] + smem[5] + smem[6] + smem[7];
        }
    } else {
        for (int i = (b - 256) * 256 + threadIdx.x; i < 131328; i += 64 * 256) {
            const void* s; int off;
            if      (i < 49152)  { s = qA; off = i; }
            else if (i < 98304)  { s = qB; off = i - 49152; }
            else if (i < 114688) { s = oA; off = i - 98304; }
            else if (i < 131072) { s = oB; off = i - 114688; }
            else if (i < 131200) { s = bA; off = i - 131072; }
            else                 { s = bB; off = i - 131200; }
            Wc[i] = f2bf(ldf(s, off, f32));
        }
    }
}

// ---------------- fused GroupNorm-apply + KV GEMM ----------------------------
// Per block: 16-pixel tile of stream z. Phase A: normalize into f32 LDS tile,
// write global xn (attn Q-recompute needs it) + bf16 B-tile in LDS.
// Phase B: K/V GEMM straight from LDS (verified fragment pattern; o-tiles
// pre-filtered to K/V rows only — Q rows are recomputed in attn).
__global__ void gnqkv_kernel(const void* __restrict__ xA, const void* __restrict__ xB,
                             const void* __restrict__ gw, const void* __restrict__ gb,
                             const float* __restrict__ raw2,
                             const unsigned short* __restrict__ Wc,
                             unsigned short* __restrict__ xn,
                             unsigned short* __restrict__ Kt,
                             unsigned short* __restrict__ Vp) {
    const bool f32 = detect_f32(xA);
    const int z = blockIdx.y;
    const int p0 = blockIdx.x * 16;
    const void* x = z ? xB : xA;
    const int tid = threadIdx.x;
    __shared__ float st[16][2];
    __shared__ float tile[128][17];                 // 8.7 KB [c][p]
    __shared__ __align__(16) unsigned int btile[16][68];  // 4.4 KB bf16 pairs [p][c/2]
    if (tid < 16) {
        float s1 = 0.f, s2 = 0.f;
#pragma unroll
        for (int c = 0; c < 8; c++) {
            s1 += raw2[(z * 128 + tid * 8 + c) * 2];
            s2 += raw2[(z * 128 + tid * 8 + c) * 2 + 1];
        }
        const float NEL = 8.0f * HW;
        float mu = s1 / NEL;
        float var = s2 / NEL - mu * mu;
        st[tid][0] = mu;
        st[tid][1] = rsqrtf(var + 1e-5f);
    }
    __syncthreads();
    const int pl = tid & 15;
#pragma unroll
    for (int it = 0; it < 8; it++) {
        int c = it * 16 + (tid >> 4);
        float v = ldf(x, (size_t)c * HW + p0 + pl, f32);
        tile[c][pl] = (v - st[c >> 3][0]) * st[c >> 3][1] * ldf(gw, c, f32)
                    + ldf(gb, c, f32);
    }
    __syncthreads();
    unsigned int* xo = (unsigned int*)(xn + (size_t)z * HW * CC);
#pragma unroll
    for (int k = 0; k < 4; k++) {
        int idx = tid + k * 256;
        int p = idx >> 6, c2 = idx & 63;
        unsigned lo = (unsigned)f2bf(tile[2 * c2][p]);
        unsigned hi = (unsigned)f2bf(tile[2 * c2 + 1][p]);
        unsigned pr = lo | (hi << 16);
        xo[(size_t)(p0 + p) * 64 + c2] = pr;
        btile[p][c2] = pr;
    }
    __syncthreads();
    // ---- phase B: K/V GEMM from LDS (16 useful o-tiles over 4 waves) ----
    const int wave = tid >> 6, lane = tid & 63;
    const int quad = lane >> 4, col = lane & 15;
    const unsigned short* Wq = Wc + (size_t)z * 49152;
    const unsigned short* bt = (const unsigned short*)btile;  // row = 136 shorts
#pragma unroll
    for (int i = 0; i < 4; i++) {
        int idx = wave * 4 + i;
        int h = idx >> 2;
        int o0 = (6 * h + 2 + (idx & 3)) * 16;   // skips rr<32 (Q) tiles
        f32x4 acc = {0.f, 0.f, 0.f, 0.f};
#pragma unroll
        for (int kc = 0; kc < 4; kc++) {
            short8 a = *(const short8*)(Wq + (size_t)(o0 + col) * CC + kc * 32 + quad * 8);
            short8 b = *(const short8*)(bt + col * 136 + kc * 32 + quad * 8);
            acc = __builtin_amdgcn_mfma_f32_16x16x32_bf16(a, b, acc, 0, 0, 0);
        }
#pragma unroll
        for (int r = 0; r < 4; r++) {
            int o = o0 + quad * 4 + r;
            int rr = o % 96;                      // in [32,96)
            int p = p0 + col;
            unsigned short vb = f2bf(acc[r]);
            if (rr < 64) {
                Kt[((size_t)(z * NH + h) * HW + p) * DH + (rr - 32)] = vb;
            } else {
                int d = rr - 64;
                int jb = p >> 6, jl = p & 63;
                int sub = jl >> 5, jm = jl & 31;
                int qp, jj;
                if (jm < 16) { qp = jm >> 2; jj = jm & 3; }
                else         { qp = (jm - 16) >> 2; jj = 4 + ((jm - 16) & 3); }
                int frag  = (d >> 4) + sub * 2;
                int lanep = qp * 16 + (d & 15);
                Vp[(((size_t)(z * NH + h) * 64 + jb) * 2048)
                   + frag * 512 + lanep * 8 + jj] = vb;
            }
        }
    }
}

// ---------------- Flash attention: i-tile 32, 8 waves = 8 j-chunks of 512 ----
__global__ __launch_bounds__(512, 4) void attn_kernel(
        const unsigned short* __restrict__ Wc,
        const unsigned short* __restrict__ xn,
        const unsigned short* __restrict__ Kt_all,
        const unsigned short* __restrict__ Vp_all,
        unsigned short* __restrict__ OT_all) {
    const int z = blockIdx.z, h = blockIdx.y;
    const int tid = threadIdx.x;
    const int wave = tid >> 6, lane = tid & 63;
    const int quad = lane >> 4, col = lane & 15;
    const int sc = wave;            // j-chunk 0..7 (512 j each)
    const int zq = 1 - z;
    const unsigned short* Kt = Kt_all + (size_t)(z * NH + h) * HW * DH;
    const unsigned short* Vp = Vp_all + (size_t)(z * NH + h) * 64 * 2048;
    unsigned short* OT = OT_all + (size_t)z * HW * CC;

    const int i0 = blockIdx.x * 32;

    __shared__ __align__(16) short qlds[32][40];           // 2.5 KB (pad 40)
    __shared__ float ldsO[8][2][32][17];                   // 34.8 KB
    __shared__ float ldsl[8][32];                          // 1 KB

    // ---- recompute Q: waves 0..3 -> (subtile w>>1, d-half w&1), pre-scaled ---
    if (wave < 4) {
        const float kscale = 0.12751569782174257f;  // (1/sqrt(128))*log2(e)
        const int stq = wave >> 1, dcq = wave & 1;
        const unsigned short* Wq = Wc + (size_t)zq * 49152 + (size_t)(96 * h) * CC;
        const unsigned short* xq = xn + (size_t)zq * HW * CC;
        f32x4 qa = {0.f, 0.f, 0.f, 0.f};
#pragma unroll
        for (int kc = 0; kc < 4; kc++) {
            short8 a = *(const short8*)(Wq + (size_t)(dcq * 16 + col) * CC + kc * 32 + quad * 8);
            short8 b = *(const short8*)(xq + (size_t)(i0 + stq * 16 + col) * CC + kc * 32 + quad * 8);
            qa = __builtin_amdgcn_mfma_f32_16x16x32_bf16(a, b, qa, 0, 0, 0);
        }
#pragma unroll
        for (int r = 0; r < 4; r++)
            qlds[stq * 16 + col][dcq * 16 + quad * 4 + r] = (short)f2bf(qa[r] * kscale);
    }
    __syncthreads();

    f32x4 acc0[2], acc1[2];
    float li[2];
#pragma unroll
    for (int s = 0; s < 2; s++) {
        acc0[s] = (f32x4){0.f, 0.f, 0.f, 0.f};
        acc1[s] = (f32x4){0.f, 0.f, 0.f, 0.f};
        li[s] = 0.f;
    }

    const int jb = sc * 512;
    for (int j0 = jb; j0 < jb + 512; j0 += 64) {
        short8 kf[4];
#pragma unroll
        for (int X = 0; X < 4; X++)
            kf[X] = *(const short8*)(Kt + (size_t)(j0 + X * 16 + col) * DH + quad * 8);
        const unsigned short* vb_ = Vp + (size_t)(j0 >> 6) * 2048 + lane * 8;
        short8 va0 = *(const short8*)(vb_);
        short8 va1 = *(const short8*)(vb_ + 512);
        short8 va2 = *(const short8*)(vb_ + 1024);
        short8 va3 = *(const short8*)(vb_ + 1536);
#pragma unroll
        for (int s = 0; s < 2; s++) {
            short8 qf = *(const short8*)(&qlds[s * 16 + col][quad * 8]);
            f32x4 zero = {0.f, 0.f, 0.f, 0.f};
            f32x4 st0 = __builtin_amdgcn_mfma_f32_16x16x32_bf16(kf[0], qf, zero, 0, 0, 0);
            f32x4 st1 = __builtin_amdgcn_mfma_f32_16x16x32_bf16(kf[1], qf, zero, 0, 0, 0);
            f32x4 st2 = __builtin_amdgcn_mfma_f32_16x16x32_bf16(kf[2], qf, zero, 0, 0, 0);
            f32x4 st3 = __builtin_amdgcn_mfma_f32_16x16x32_bf16(kf[3], qf, zero, 0, 0, 0);
            float e[16], l0 = 0.f, l1 = 0.f;
#pragma unroll
            for (int r = 0; r < 4; r++) {
                e[r]      = fexp2(st0[r]);
                e[4 + r]  = fexp2(st1[r]);
                e[8 + r]  = fexp2(st2[r]);
                e[12 + r] = fexp2(st3[r]);
                l0 += e[r] + e[4 + r];
                l1 += e[8 + r] + e[12 + r];
            }
            li[s] += l0 + l1;
            short8 pb0 = pack8(&e[0]);
            short8 pb1 = pack8(&e[8]);
            acc0[s] = __builtin_amdgcn_mfma_f32_16x16x32_bf16(va0, pb0, acc0[s], 0, 0, 0);
            acc1[s] = __builtin_amdgcn_mfma_f32_16x16x32_bf16(va1, pb0, acc1[s], 0, 0, 0);
            acc0[s] = __builtin_amdgcn_mfma_f32_16x16x32_bf16(va2, pb1, acc0[s], 0, 0, 0);
            acc1[s] = __builtin_amdgcn_mfma_f32_16x16x32_bf16(va3, pb1, acc1[s], 0, 0, 0);
        }
    }
#pragma unroll
    for (int s = 0; s < 2; s++) {
        li[s] += __shfl_xor(li[s], 16);
        li[s] += __shfl_xor(li[s], 32);
#pragma unroll
        for (int r = 0; r < 4; r++) {
            ldsO[sc][s][quad * 4 + r][col]      = acc0[s][r];
            ldsO[sc][s][16 + quad * 4 + r][col] = acc1[s][r];
        }
        if (quad == 0) ldsl[sc][s * 16 + col] = li[s];
    }
    __syncthreads();
    // ---- combine 8 chunks (plain sums; bounded logits) ----
#pragma unroll
    for (int k = 0; k < 2; k++) {
        int idx = tid + k * 512;
        int il = idx >> 5, d = idx & 31;
        int itc = il >> 4, cc2 = il & 15;
        float L = 0.f, O = 0.f;
#pragma unroll
        for (int c8 = 0; c8 < 8; c8++) {
            L += ldsl[c8][il];
            O += ldsO[c8][itc][d][cc2];
        }
        OT[(size_t)(i0 + il) * CC + h * DH + d] = f2bf(O / L);
    }
}

// ---------------- Out proj + bias + f32 residual (stats inline) --------------
__global__ void proj_kernel(const unsigned short* __restrict__ Wc,
                            const unsigned short* __restrict__ OT_all,
                            const void* __restrict__ xA,
                            const void* __restrict__ xB,
                            const void* __restrict__ gw,
                            const void* __restrict__ gb,
                            const float* __restrict__ raw2,
                            float* __restrict__ out) {
    const bool f32 = detect_f32(xA);
    const int z = blockIdx.z;
    const unsigned short* Wp = Wc + 98304 + (size_t)z * 16384;
    const unsigned short* bp = Wc + 131072 + (size_t)z * 128;
    const void* xz = z ? xB : xA;
    const int tid = threadIdx.x;
    __shared__ float st[16][2];
    if (tid < 16) {
        float s1 = 0.f, s2 = 0.f;
#pragma unroll
        for (int c = 0; c < 8; c++) {
            s1 += raw2[(z * 128 + tid * 8 + c) * 2];
            s2 += raw2[(z * 128 + tid * 8 + c) * 2 + 1];
        }
        const float NEL = 8.0f * HW;
        float mu = s1 / NEL;
        float var = s2 / NEL - mu * mu;
        st[tid][0] = mu;
        st[tid][1] = rsqrtf(var + 1e-5f);
    }
    __syncthreads();
    const int o0 = blockIdx.x * 16;
    const int w = tid >> 6, lane = tid & 63;
    const int quad = lane >> 4, col = lane & 15;
    const int p0 = blockIdx.y * 64 + w * 16;
    const unsigned short* ob = OT_all + (size_t)z * HW * CC;
    f32x4 acc = {0.f, 0.f, 0.f, 0.f};
#pragma unroll
    for (int kc = 0; kc < 4; kc++) {
        short8 a = *(const short8*)(Wp + (size_t)(o0 + col) * CC + kc * 32 + quad * 8);
        short8 b = *(const short8*)(ob + (size_t)(p0 + col) * CC + kc * 32 + quad * 8);
        acc = __builtin_amdgcn_mfma_f32_16x16x32_bf16(a, b, acc, 0, 0, 0);
    }
    const int p = p0 + col;
#pragma unroll
    for (int r = 0; r < 4; r++) {
        int o = o0 + quad * 4 + r;
        float xv = ldf(xz, (size_t)o * HW + p, f32);
        float res = (xv - st[o >> 3][0]) * st[o >> 3][1] * ldf(gw, o, f32)
                  + ldf(gb, o, f32);
        out[(size_t)z * CC * HW + (size_t)o * HW + p] = acc[r] + bf2f(bp[o]) + res;
    }
}

extern "C" void kernel_launch(void* const* d_in, const int* in_sizes, int n_in,
                              void* d_out, int out_size, void* d_ws, size_t ws_size,
                              hipStream_t stream) {
    (void)in_sizes; (void)n_in; (void)out_size; (void)ws_size;
    const void* xA    = d_in[0];
    const void* xB    = d_in[1];
    const void* gnw   = d_in[2];
    const void* gnb   = d_in[3];
    const void* qkvAw = d_in[4];
    const void* outAw = d_in[5];
    const void* outAb = d_in[6];
    const void* qkvBw = d_in[7];
    const void* outBw = d_in[8];
    const void* outBb = d_in[9];

    // workspace: 9 MB total
    char* ws = (char*)d_ws;
    float*          raw2 = (float*)(ws);                        // 2 KB [2][128][2]
    unsigned short* Wc   = (unsigned short*)(ws + 4096);        // 257 KB
    unsigned short* Kt   = (unsigned short*)(ws + (1u << 20));  // 2 MB [2][4][4096][32]
    unsigned short* Vp   = (unsigned short*)(ws + (3u << 20));  // 2 MB swizzled V
    unsigned short* OT   = (unsigned short*)(ws + (5u << 20));  // 2 MB [2][4096][128]
    unsigned short* xn   = (unsigned short*)(ws + (7u << 20));  // 2 MB [2][4096][128]

    prep_kernel<<<320, 256, 0, stream>>>(xA, xB, qkvAw, qkvBw, outAw, outBw,
                                         outAb, outBb, raw2, Wc);
    gnqkv_kernel<<<dim3(256, 2), 256, 0, stream>>>(xA, xB, gnw, gnb, raw2, Wc,
                                                   xn, Kt, Vp);
    attn_kernel<<<dim3(128, NH, 2), 512, 0, stream>>>(Wc, xn, Kt, Vp, OT);
    proj_kernel<<<dim3(8, 64, 2), 256, 0, stream>>>(Wc, OT, xA, xB, gnw, gnb,
                                                    raw2, (float*)d_out);
}